// Round 1
// 302.212 us; speedup vs baseline: 1.0065x; 1.0065x over previous
//
#include <hip/hip_runtime.h>
#include <hip/hip_bf16.h>
#include <math.h>

typedef __bf16 bf16_8 __attribute__((ext_vector_type(8)));
typedef float f32x4 __attribute__((ext_vector_type(4)));

#define NDIM 1024

__device__ static inline void async_copy16(const void* g, void* l) {
  __builtin_amdgcn_global_load_lds(
      (__attribute__((address_space(1))) void*)g,
      (__attribute__((address_space(3))) void*)l, 16, 0, 0);
}

// ======================= FAST PATH (needs 66 MB workspace) =======================
// Operands live in global memory as pre-blocked 16 KB "LDS images": tile [128 rows][64 k]
// bf16, with the k-slot (16B) XOR-swizzled by (row&7) so MFMA fragment ds_read_b128s are
// bank-conflict-free. global_load_lds then stages them with linear 1 KB chunks.

// A[m][k] = s(m) * cos(pi * m * (2k+1) / 2048), blocked+swizzled.
__global__ void gen_dct_blocked(__bf16* __restrict__ A) {
  int idx = blockIdx.x * blockDim.x + threadIdx.x;  // 0..131071
  int m = idx >> 7;        // DCT output row 0..1023
  int ks = idx & 127;      // k-slot index (8 bf16 per slot)
  int kt = ks >> 3, s = ks & 7;
  int mt = m >> 7, r = m & 127;
  float sc = (m == 0) ? 0.03125f : 0.04419417382415922f;
  int kbase = kt * 64 + s * 8;
  bf16_8 v;
#pragma unroll
  for (int q = 0; q < 8; q++) {
    int k = kbase + q;
    int t = (m * (2 * k + 1)) & 4095;               // exact phase mod 2*pi
    float ang = (float)t * 1.5339807878856412e-3f;  // pi/2048
    v[q] = (__bf16)(sc * cosf(ang));
  }
  *(bf16_8*)(A + (((size_t)(mt * 16 + kt)) << 13) + r * 64 + ((s ^ (r & 7)) << 3)) = v;
}

// x[b][k][n] f32  ->  blocked bf16 images B[(b*8+nt)*16+kt] = [n=128][k=64] swizzled.
#define TP 132  // padded LDS row (f32) : conflict-free column reads, 16B-aligned rows
__global__ __launch_bounds__(256) void transpose_cvt(const float* __restrict__ x,
                                                     __bf16* __restrict__ B) {
  __shared__ float T[64 * TP];
  const int t = threadIdx.x;
  const int kt = blockIdx.x, nt = blockIdx.y, b = blockIdx.z;
  const float* xb =
      x + (size_t)b * (NDIM * NDIM) + (size_t)kt * 64 * NDIM + nt * 128;
  // stage tile [k=64][n=128] f32 (coalesced: 2 full 512B rows per wave-instruction)
  {
    const int kr = t >> 5;        // 0..7
    const int c4 = (t & 31) * 4;  // float col, 16B chunk
#pragma unroll
    for (int u = 0; u < 8; u++) {
      int k = u * 8 + kr;
      f32x4 v = *(const f32x4*)(xb + (size_t)k * NDIM + c4);
      *(f32x4*)(&T[k * TP + c4]) = v;
    }
  }
  __syncthreads();
  __bf16* img = B + (((size_t)((b * 8 + nt) * 16 + kt)) << 13);
#pragma unroll
  for (int u = 0; u < 4; u++) {
    int c = t * 4 + u;  // 16B output chunk id; thread owns 64 contiguous bytes
    int r = c >> 3, sp = c & 7;
    int s = sp ^ (r & 7);  // data slot stored at position sp
    bf16_8 v;
#pragma unroll
    for (int q = 0; q < 8; q++) v[q] = (__bf16)T[(s * 8 + q) * TP + r];
    *(bf16_8*)(img + c * 8) = v;
  }
}

// 128x128 tile, BK=64, double-buffered, DMA-only staging, swizzled frag reads.
__global__ __launch_bounds__(256) void dct_gemm2(const __bf16* __restrict__ A,
                                                 const __bf16* __restrict__ B,
                                                 float* __restrict__ out) {
  __shared__ __align__(1024) __bf16 As[2][128 * 64];  // 2 x 16 KB
  __shared__ __align__(1024) __bf16 Bs[2][128 * 64];  // 2 x 16 KB
  const int t = threadIdx.x;
  const int w = t >> 6, lane = t & 63;
  const int nt = blockIdx.x, mt = blockIdx.y, b = blockIdx.z;

  // per-lane global sources (images are literal LDS images: linear copy)
  const __bf16* ag = A + (((size_t)mt * 16) << 13) + w * 2048 + lane * 8;
  const __bf16* bg =
      B + (((size_t)((b * 8 + nt) * 16)) << 13) + w * 2048 + lane * 8;

  const int r16 = lane & 15;
  const int g8 = (lane >> 4) << 3;
  const int wm = (w & 1) << 6, wn = (w >> 1) << 6;
  const int xr = (r16 & 7) << 3;  // swizzle term (element units)
  const int kof0 = g8 ^ xr;       // k-half 0
  const int kof1 = (32 + g8) ^ xr;  // k-half 1

  // prologue: stage kt=0 into buf 0 (4 A-chunks + 4 B-chunks per wave)
#pragma unroll
  for (int i = 0; i < 4; i++) {
    async_copy16(ag + i * 512, &As[0][w * 2048 + i * 512]);
    async_copy16(bg + i * 512, &Bs[0][w * 2048 + i * 512]);
  }
  __syncthreads();  // drains vmcnt: tile 0 resident

  f32x4 acc[4][4] = {};

  for (int kt = 0; kt < 16; kt++) {
    const int cur = kt & 1;
    if (kt < 15) {  // prefetch next tile into the other buffer
      const __bf16* an = ag + (size_t)(kt + 1) * 8192;
      const __bf16* bn = bg + (size_t)(kt + 1) * 8192;
      const int nb = cur ^ 1;
#pragma unroll
      for (int i = 0; i < 4; i++) {
        async_copy16(an + i * 512, &As[nb][w * 2048 + i * 512]);
        async_copy16(bn + i * 512, &Bs[nb][w * 2048 + i * 512]);
      }
    }
    const __bf16* as = &As[cur][0];
    const __bf16* bs = &Bs[cur][0];
#pragma unroll
    for (int h = 0; h < 2; h++) {
      const int kof = h ? kof1 : kof0;
      bf16_8 af[4], bfr[4];
#pragma unroll
      for (int i = 0; i < 4; i++)
        af[i] = *(const bf16_8*)(as + (wm + i * 16 + r16) * 64 + kof);
#pragma unroll
      for (int j = 0; j < 4; j++)
        bfr[j] = *(const bf16_8*)(bs + (wn + j * 16 + r16) * 64 + kof);
#pragma unroll
      for (int i = 0; i < 4; i++)
#pragma unroll
        for (int j = 0; j < 4; j++)
          acc[i][j] = __builtin_amdgcn_mfma_f32_16x16x32_bf16(af[i], bfr[j],
                                                              acc[i][j], 0, 0, 0);
    }
    __syncthreads();  // next tile staged (vmcnt drain) + cur reads done block-wide
  }

  // epilogue: C/D layout col = lane&15, row = (lane>>4)*4 + reg
  float* ob = out + (size_t)b * (NDIM * NDIM);
  const int rbase = (lane >> 4) << 2;
  const int cofs = lane & 15;
  const int m0 = mt * 128, n0 = nt * 128;
#pragma unroll
  for (int i = 0; i < 4; i++)
#pragma unroll
    for (int rr = 0; rr < 4; rr++) {
      int row = m0 + wm + i * 16 + rbase + rr;
#pragma unroll
      for (int j = 0; j < 4; j++) {
        int col = n0 + wn + j * 16 + cofs;
        ob[(size_t)row * NDIM + col] = acc[i][j][rr];
      }
    }
}

// ======================= FALLBACK PATH (small workspace) =======================
#define BM 128
#define BN 128
#define BK 32
#define BSTRIDE 40

__global__ void gen_dct_mat(__bf16* __restrict__ C) {
  int idx = blockIdx.x * blockDim.x + threadIdx.x;
  int k = idx >> 10;
  int j = idx & 1023;
  int t = (k * (2 * j + 1)) & 4095;
  float ang = (float)t * 1.5339807878856412e-3f;
  float s = (k == 0) ? 0.03125f : 0.04419417382415922f;
  C[idx] = (__bf16)(s * cosf(ang));
}

__global__ __launch_bounds__(256) void dct_gemm(
    const float* __restrict__ x, const __bf16* __restrict__ A,
    float* __restrict__ out) {
  __shared__ __align__(64) __bf16 Asm[BM * BK];
  __shared__ __align__(64) __bf16 Bsm[BN * BSTRIDE];

  const int t = threadIdx.x;
  const int wave = t >> 6;
  const int lane = t & 63;
  const int bb = blockIdx.z;
  const int m0 = blockIdx.y * BM;
  const int n0 = blockIdx.x * BN;

  const __bf16* Ag0 =
      A + (size_t)(m0 + wave * 16 + (lane >> 2)) * NDIM + ((lane & 3) * 8);
  const __bf16* Ag1 = Ag0 + (size_t)64 * NDIM;
  __bf16* Al0 = Asm + (wave * 16) * BK;
  __bf16* Al1 = Asm + (64 + wave * 16) * BK;

  const int bc = t & 127;
  const int bjg = t >> 7;
  const float* xs =
      x + (size_t)bb * (NDIM * NDIM) + (size_t)(bjg * 16) * NDIM + (n0 + bc);
  bf16_8* bs0 = (bf16_8*)(Bsm + bc * BSTRIDE + bjg * 16);
  bf16_8* bs1 = (bf16_8*)(Bsm + bc * BSTRIDE + bjg * 16 + 8);

  const int row16 = lane & 15;
  const int kq8 = (lane >> 4) * 8;
  const int wm = (wave & 1) * 64;
  const int wn = (wave >> 1) * 64;

  f32x4 acc[4][4] = {};

  for (int k0 = 0; k0 < NDIM; k0 += BK) {
    __syncthreads();
    async_copy16(Ag0 + k0, Al0);
    async_copy16(Ag1 + k0, Al1);

    const float* xp = xs + (size_t)k0 * NDIM;
    bf16_8 v0, v1;
#pragma unroll
    for (int q = 0; q < 8; q++) {
      v0[q] = (__bf16)xp[(size_t)q * NDIM];
      v1[q] = (__bf16)xp[(size_t)(q + 8) * NDIM];
    }
    *bs0 = v0;
    *bs1 = v1;
    __syncthreads();

    bf16_8 af[4], bfr[4];
#pragma unroll
    for (int i = 0; i < 4; i++)
      af[i] = *(const bf16_8*)(Asm + (wm + i * 16 + row16) * BK + kq8);
#pragma unroll
    for (int j = 0; j < 4; j++)
      bfr[j] = *(const bf16_8*)(Bsm + (wn + j * 16 + row16) * BSTRIDE + kq8);
#pragma unroll
    for (int i = 0; i < 4; i++)
#pragma unroll
      for (int j = 0; j < 4; j++)
        acc[i][j] = __builtin_amdgcn_mfma_f32_16x16x32_bf16(af[i], bfr[j],
                                                            acc[i][j], 0, 0, 0);
  }

  float* ob = out + (size_t)bb * (NDIM * NDIM);
  const int rbase = (lane >> 4) * 4;
  const int cofs = lane & 15;
#pragma unroll
  for (int i = 0; i < 4; i++) {
#pragma unroll
    for (int r = 0; r < 4; r++) {
      int row = m0 + wm + i * 16 + rbase + r;
#pragma unroll
      for (int j = 0; j < 4; j++) {
        int col = n0 + wn + j * 16 + cofs;
        ob[(size_t)row * NDIM + col] = acc[i][j][r];
      }
    }
  }
}

extern "C" void kernel_launch(void* const* d_in, const int* in_sizes, int n_in,
                              void* d_out, int out_size, void* d_ws,
                              size_t ws_size, hipStream_t stream) {
  const float* x = (const float*)d_in[0];
  float* out = (float*)d_out;

  const size_t need = (size_t)66 * 1024 * 1024;  // 2 MB A-blocked + 64 MB x-blocked
  if (ws_size >= need) {
    __bf16* Ab = (__bf16*)d_ws;
    __bf16* Bb = Ab + (size_t)1024 * 1024;  // skip 2 MB
    gen_dct_blocked<<<dim3(512), dim3(256), 0, stream>>>(Ab);
    transpose_cvt<<<dim3(16, 8, 32), dim3(256), 0, stream>>>(x, Bb);
    dct_gemm2<<<dim3(8, 8, 32), dim3(256), 0, stream>>>(Ab, Bb, out);
  } else {
    __bf16* Cmat = (__bf16*)d_ws;  // 2 MB
    gen_dct_mat<<<dim3((NDIM * NDIM) / 256), dim3(256), 0, stream>>>(Cmat);
    dct_gemm<<<dim3(NDIM / BN, NDIM / BM, 32), dim3(256), 0, stream>>>(x, Cmat,
                                                                       out);
  }
}

// Round 2
// 279.719 us; speedup vs baseline: 1.0874x; 1.0804x over previous
//
#include <hip/hip_runtime.h>
#include <hip/hip_bf16.h>
#include <math.h>

typedef __bf16 bf16_8 __attribute__((ext_vector_type(8)));
typedef __bf16 bf16_4 __attribute__((ext_vector_type(4)));
typedef float f32x4 __attribute__((ext_vector_type(4)));

#define NDIM 1024

__device__ static inline void async_copy16(const void* g, void* l) {
  __builtin_amdgcn_global_load_lds(
      (__attribute__((address_space(1))) void*)g,
      (__attribute__((address_space(3))) void*)l, 16, 0, 0);
}

// ======================= FAST PATH (needs 66 MB workspace) =======================
// DCT symmetry fold: C[k][1023-j] = (-1)^k * C[k][j], so
//   out[2k'][n]   = sum_{j<512} C[2k'][j]   * (x[j][n] + x[1023-j][n])
//   out[2k'+1][n] = sum_{j<512} C[2k'+1][j] * (x[j][n] - x[1023-j][n])
// -> two 512x1024x512 GEMMs (half the FLOPs), operands pre-blocked as 16 KB
// swizzled "LDS images" ([128 rows][64 k] bf16, 16B slot s stored at s^(r&7)).

// Ae (sel=0) / Ao (sel=1): half-matrix [512 m'][512 j], blocked+swizzled.
__global__ void gen_dct_fold(__bf16* __restrict__ A) {
  int idx = blockIdx.x * blockDim.x + threadIdx.x;  // 0..65535
  int sel = idx >> 15;
  int rem = idx & 32767;
  int mp = rem >> 6;    // m' 0..511 (row within half-matrix)
  int slot = rem & 63;  // 16B slot within 512-wide j row
  int kt = slot >> 3, s = slot & 7;
  int k = 2 * mp + sel;  // actual DCT row
  int r = mp & 127, mtp = mp >> 7;
  float sc = (k == 0) ? 0.03125f : 0.04419417382415922f;
  int jb = kt * 64 + s * 8;
  bf16_8 v;
#pragma unroll
  for (int q = 0; q < 8; q++) {
    int j = jb + q;
    int t = (k * (2 * j + 1)) & 4095;               // exact phase mod 2*pi
    float ang = (float)t * 1.5339807878856412e-3f;  // pi/2048
    v[q] = (__bf16)(sc * cosf(ang));
  }
  *(bf16_8*)(A + (((size_t)(sel * 32 + mtp * 8 + kt)) << 13) + r * 64 +
             ((s ^ (r & 7)) << 3)) = v;
}

// x[b][j][n] f32 -> folded U/V blocked bf16 images.
// Image (b, sel, nt, kt) = [n=128 rows][j'=64] swizzled, at
//   B + ((b*2+sel)*64 + nt*8 + kt) * 8192.
__global__ __launch_bounds__(256) void fold_cvt(const float* __restrict__ x,
                                                __bf16* __restrict__ B) {
  __shared__ __bf16 Tu[64 * 128];  // [j_local][n] bf16, 16 KB
  __shared__ __bf16 Tv[64 * 128];
  const int t = threadIdx.x;
  const int kt = blockIdx.x, nt = blockIdx.y, b = blockIdx.z;
  const float* xb = x + (size_t)b * (NDIM * NDIM) + nt * 128;
  const int kr = t >> 5;        // 0..7
  const int c4 = (t & 31) * 4;  // float col (16B chunk)
  const int jb = kt * 64;         // top rows j = jb + k
  const int mb = 1023 - kt * 64;  // mirror rows = mb - k
#pragma unroll
  for (int u = 0; u < 8; u++) {
    int k = u * 8 + kr;
    f32x4 a = *(const f32x4*)(xb + (size_t)(jb + k) * NDIM + c4);
    f32x4 m = *(const f32x4*)(xb + (size_t)(mb - k) * NDIM + c4);
    f32x4 su = a + m, dv = a - m;
    bf16_4 wu, wv;
#pragma unroll
    for (int i = 0; i < 4; i++) {
      wu[i] = (__bf16)su[i];
      wv[i] = (__bf16)dv[i];
    }
    *(bf16_4*)(&Tu[k * 128 + c4]) = wu;  // 2-way/bank -> free
    *(bf16_4*)(&Tv[k * 128 + c4]) = wv;
  }
  __syncthreads();
  __bf16* outU = B + (((size_t)(b * 2 + 0) * 64 + nt * 8 + kt) << 13);
  __bf16* outV = B + (((size_t)(b * 2 + 1) * 64 + nt * 8 + kt) << 13);
#pragma unroll
  for (int u = 0; u < 4; u++) {
    int c = t * 4 + u;  // 16B output chunk; thread owns 64 contiguous bytes
    int r = c >> 3, sp = c & 7;
    int s = sp ^ (r & 7);  // data slot stored at position sp
    bf16_8 vU, vV;
#pragma unroll
    for (int q = 0; q < 8; q++) {  // column read: same-address broadcast, free
      vU[q] = Tu[(s * 8 + q) * 128 + r];
      vV[q] = Tv[(s * 8 + q) * 128 + r];
    }
    *(bf16_8*)(outU + c * 8) = vU;
    *(bf16_8*)(outV + c * 8) = vV;
  }
}

// 128x128 tile, K=512 (8 steps of BK=64), double-buffered, DMA staging,
// swizzled conflict-free frag reads. blockIdx.y: sel = y&1 (even/odd), mtp = y>>1.
__global__ __launch_bounds__(256) void dct_gemm3(const __bf16* __restrict__ A,
                                                 const __bf16* __restrict__ B,
                                                 float* __restrict__ out) {
  __shared__ __align__(1024) __bf16 As[2][128 * 64];  // 2 x 16 KB
  __shared__ __align__(1024) __bf16 Bs[2][128 * 64];
  const int t = threadIdx.x;
  const int w = t >> 6, lane = t & 63;
  const int nt = blockIdx.x, b = blockIdx.z;
  const int sel = blockIdx.y & 1, mtp = blockIdx.y >> 1;

  const __bf16* ag =
      A + (((size_t)(sel * 32 + mtp * 8)) << 13) + w * 2048 + lane * 8;
  const __bf16* bg =
      B + (((size_t)(b * 2 + sel) * 64 + nt * 8) << 13) + w * 2048 + lane * 8;

  const int r16 = lane & 15;
  const int g8 = (lane >> 4) << 3;
  const int wm = (w & 1) << 6, wn = (w >> 1) << 6;
  const int xr = (r16 & 7) << 3;    // swizzle term (element units)
  const int kof0 = g8 ^ xr;         // k-half 0
  const int kof1 = (32 + g8) ^ xr;  // k-half 1

#pragma unroll
  for (int i = 0; i < 4; i++) {
    async_copy16(ag + i * 512, &As[0][w * 2048 + i * 512]);
    async_copy16(bg + i * 512, &Bs[0][w * 2048 + i * 512]);
  }
  __syncthreads();  // tile 0 resident

  f32x4 acc[4][4] = {};

  for (int kt = 0; kt < 8; kt++) {
    const int cur = kt & 1;
    if (kt < 7) {
      const __bf16* an = ag + (size_t)(kt + 1) * 8192;
      const __bf16* bn = bg + (size_t)(kt + 1) * 8192;
      const int nb = cur ^ 1;
#pragma unroll
      for (int i = 0; i < 4; i++) {
        async_copy16(an + i * 512, &As[nb][w * 2048 + i * 512]);
        async_copy16(bn + i * 512, &Bs[nb][w * 2048 + i * 512]);
      }
    }
    const __bf16* as = &As[cur][0];
    const __bf16* bs = &Bs[cur][0];
#pragma unroll
    for (int h = 0; h < 2; h++) {
      const int kof = h ? kof1 : kof0;
      bf16_8 af[4], bfr[4];
#pragma unroll
      for (int i = 0; i < 4; i++)
        af[i] = *(const bf16_8*)(as + (wm + i * 16 + r16) * 64 + kof);
#pragma unroll
      for (int j = 0; j < 4; j++)
        bfr[j] = *(const bf16_8*)(bs + (wn + j * 16 + r16) * 64 + kof);
#pragma unroll
      for (int i = 0; i < 4; i++)
#pragma unroll
        for (int j = 0; j < 4; j++)
          acc[i][j] = __builtin_amdgcn_mfma_f32_16x16x32_bf16(af[i], bfr[j],
                                                              acc[i][j], 0, 0, 0);
    }
    __syncthreads();  // next tile staged + cur reads done block-wide
  }

  // epilogue: C/D layout col = lane&15, row_half = (lane>>4)*4 + reg;
  // physical out row = 2*row_half_global + sel (even/odd interleave).
  float* ob = out + (size_t)b * (NDIM * NDIM);
  const int rbase = (lane >> 4) << 2;
  const int cofs = lane & 15;
  const int n0 = nt * 128;
#pragma unroll
  for (int i = 0; i < 4; i++)
#pragma unroll
    for (int rr = 0; rr < 4; rr++) {
      int rh = mtp * 128 + wm + i * 16 + rbase + rr;
      int row = rh * 2 + sel;
#pragma unroll
      for (int j = 0; j < 4; j++) {
        int col = n0 + wn + j * 16 + cofs;
        ob[(size_t)row * NDIM + col] = acc[i][j][rr];
      }
    }
}

// ======================= FALLBACK PATH (small workspace) =======================
#define BM 128
#define BN 128
#define BK 32
#define BSTRIDE 40

__global__ void gen_dct_mat(__bf16* __restrict__ C) {
  int idx = blockIdx.x * blockDim.x + threadIdx.x;
  int k = idx >> 10;
  int j = idx & 1023;
  int t = (k * (2 * j + 1)) & 4095;
  float ang = (float)t * 1.5339807878856412e-3f;
  float s = (k == 0) ? 0.03125f : 0.04419417382415922f;
  C[idx] = (__bf16)(s * cosf(ang));
}

__global__ __launch_bounds__(256) void dct_gemm(
    const float* __restrict__ x, const __bf16* __restrict__ A,
    float* __restrict__ out) {
  __shared__ __align__(64) __bf16 Asm[BM * BK];
  __shared__ __align__(64) __bf16 Bsm[BN * BSTRIDE];

  const int t = threadIdx.x;
  const int wave = t >> 6;
  const int lane = t & 63;
  const int bb = blockIdx.z;
  const int m0 = blockIdx.y * BM;
  const int n0 = blockIdx.x * BN;

  const __bf16* Ag0 =
      A + (size_t)(m0 + wave * 16 + (lane >> 2)) * NDIM + ((lane & 3) * 8);
  const __bf16* Ag1 = Ag0 + (size_t)64 * NDIM;
  __bf16* Al0 = Asm + (wave * 16) * BK;
  __bf16* Al1 = Asm + (64 + wave * 16) * BK;

  const int bc = t & 127;
  const int bjg = t >> 7;
  const float* xs =
      x + (size_t)bb * (NDIM * NDIM) + (size_t)(bjg * 16) * NDIM + (n0 + bc);
  bf16_8* bs0 = (bf16_8*)(Bsm + bc * BSTRIDE + bjg * 16);
  bf16_8* bs1 = (bf16_8*)(Bsm + bc * BSTRIDE + bjg * 16 + 8);

  const int row16 = lane & 15;
  const int kq8 = (lane >> 4) * 8;
  const int wm = (wave & 1) * 64;
  const int wn = (wave >> 1) * 64;

  f32x4 acc[4][4] = {};

  for (int k0 = 0; k0 < NDIM; k0 += BK) {
    __syncthreads();
    async_copy16(Ag0 + k0, Al0);
    async_copy16(Ag1 + k0, Al1);

    const float* xp = xs + (size_t)k0 * NDIM;
    bf16_8 v0, v1;
#pragma unroll
    for (int q = 0; q < 8; q++) {
      v0[q] = (__bf16)xp[(size_t)q * NDIM];
      v1[q] = (__bf16)xp[(size_t)(q + 8) * NDIM];
    }
    *bs0 = v0;
    *bs1 = v1;
    __syncthreads();

    bf16_8 af[4], bfr[4];
#pragma unroll
    for (int i = 0; i < 4; i++)
      af[i] = *(const bf16_8*)(Asm + (wm + i * 16 + row16) * BK + kq8);
#pragma unroll
    for (int j = 0; j < 4; j++)
      bfr[j] = *(const bf16_8*)(Bsm + (wn + j * 16 + row16) * BSTRIDE + kq8);
#pragma unroll
    for (int i = 0; i < 4; i++)
#pragma unroll
      for (int j = 0; j < 4; j++)
        acc[i][j] = __builtin_amdgcn_mfma_f32_16x16x32_bf16(af[i], bfr[j],
                                                            acc[i][j], 0, 0, 0);
  }

  float* ob = out + (size_t)bb * (NDIM * NDIM);
  const int rbase = (lane >> 4) * 4;
  const int cofs = lane & 15;
#pragma unroll
  for (int i = 0; i < 4; i++) {
#pragma unroll
    for (int r = 0; r < 4; r++) {
      int row = m0 + wm + i * 16 + rbase + r;
#pragma unroll
      for (int j = 0; j < 4; j++) {
        int col = n0 + wn + j * 16 + cofs;
        ob[(size_t)row * NDIM + col] = acc[i][j][r];
      }
    }
  }
}

extern "C" void kernel_launch(void* const* d_in, const int* in_sizes, int n_in,
                              void* d_out, int out_size, void* d_ws,
                              size_t ws_size, hipStream_t stream) {
  const float* x = (const float*)d_in[0];
  float* out = (float*)d_out;

  const size_t need = (size_t)66 * 1024 * 1024;  // 2 MB A + 64 MB folded U/V
  if (ws_size >= need) {
    __bf16* Ab = (__bf16*)d_ws;                       // 2*512*512 bf16 = 1 MB
    __bf16* Bb = (__bf16*)((char*)d_ws + (size_t)2 * 1024 * 1024);  // 64 MB
    gen_dct_fold<<<dim3(256), dim3(256), 0, stream>>>(Ab);
    fold_cvt<<<dim3(8, 8, 32), dim3(256), 0, stream>>>(x, Bb);
    dct_gemm3<<<dim3(8, 8, 32), dim3(256), 0, stream>>>(Ab, Bb, out);
  } else {
    __bf16* Cmat = (__bf16*)d_ws;  // 2 MB
    gen_dct_mat<<<dim3((NDIM * NDIM) / 256), dim3(256), 0, stream>>>(Cmat);
    dct_gemm<<<dim3(NDIM / BN, NDIM / BM, 32), dim3(256), 0, stream>>>(x, Cmat,
                                                                       out);
  }
}